// Round 14
// baseline (403.852 us; speedup 1.0000x reference)
//
#include <hip/hip_runtime.h>

#define BATCH 1024
#define TT    200
#define EE    100
#define HH    200
#define GG    600   // 3*HH
#define NI    50000
#define NKT   7     // scan k-tiles: 224 = 7*32 (K=200 padded; col 200 = constant 1 for bhn fold)
#define KPAD  224
#define HSTR  264   // LDS h row stride in f16
#define NTILE3 3125 // 50000/16 output n-tiles
#define NTW   50    // ewi n'-tiles: N'=800 = 50*16
#define KTW   4     // ewi k-tiles: K=100 padded to 128

typedef _Float16 half8 __attribute__((ext_vector_type(8)));
typedef _Float16 half4v __attribute__((ext_vector_type(4)));
typedef float   float4v __attribute__((ext_vector_type(4)));

static __device__ __forceinline__ float4v mfma16(half8 a, half8 b, float4v c) {
    return __builtin_amdgcn_mfma_f32_16x16x32_f16(a, b, c, 0, 0, 0);
}

#if __has_builtin(__builtin_amdgcn_rcpf)
static __device__ __forceinline__ float fastrcp(float x) { return __builtin_amdgcn_rcpf(x); }
#else
static __device__ __forceinline__ float fastrcp(float x) { return 1.f / x; }
#endif

static __device__ __forceinline__ float sigm(float x) {
    return fastrcp(1.f + __expf(-x));
}
static __device__ __forceinline__ float tanh_fast(float x) {
    float e = __expf(2.f * fabsf(x));
    float t = 1.f - 2.f * fastrcp(e + 1.f);
    return __builtin_copysignf(t, x);
}

// ---------------- K0: fused repack of Wi (+biP) and Wh (+bhn fold) into f16 MFMA B-frags ----
// bx < 200: Wif[(nt*4+kt)*64+lane], n'=4c+g packing; bx >= 200: Whf (48 gate-tiles x 7 kt).
// bhn fold: n-gate (g==2) row k==200 carries bhn[col]; scan keeps h[200] == 1 so the MFMA
// accumulates bhn into aN directly.
__global__ __launch_bounds__(64) void repack_all(const float* __restrict__ Wi,
                                                 const float* __restrict__ bi,
                                                 const float* __restrict__ Wh,
                                                 const float* __restrict__ bhn,
                                                 half8* __restrict__ Wif,
                                                 float* __restrict__ biP,
                                                 half8* __restrict__ Whf) {
    const int bx   = blockIdx.x;
    const int lane = threadIdx.x;
    const int l15  = lane & 15;
    const int lhi  = lane >> 4;
    if (bx < NTW * KTW) {
        const int kt = bx & 3;
        const int nt = bx >> 2;
        const int np = nt * 16 + l15;     // n' in [0,800)
        const int c  = np >> 2;
        const int g  = np & 3;
        half8 v;
        #pragma unroll
        for (int j = 0; j < 8; ++j) {
            int k = kt * 32 + lhi * 8 + j;
            float w = (k < EE && g < 3) ? Wi[(size_t)k * GG + g * HH + c] : 0.f;
            v[j] = (_Float16)w;
        }
        Wif[(size_t)bx * 64 + lane] = v;
        if (kt == 0 && lhi == 0)
            biP[np] = (g < 3) ? bi[g * HH + c] : 0.f;
    } else {
        const int b2   = bx - NTW * KTW;   // 0..335
        const int kt   = b2 % NKT;
        const int tile = b2 / NKT;
        const int g    = tile / 16;
        const int tc   = tile % 16;
        const int col  = tc * 16 + l15;
        half8 v;
        #pragma unroll
        for (int j = 0; j < 8; ++j) {
            int k = kt * 32 + lhi * 8 + j;
            float w = 0.f;
            if (col < HH) {
                if (k < HH)                      w = Wh[(size_t)k * GG + g * HH + col];
                else if (g == 2 && k == HH)      w = bhn[col];   // bhn fold row
            }
            v[j] = (_Float16)w;
        }
        Whf[(size_t)b2 * 64 + lane] = v;
    }
}

// ---------------- K1: EWi16 = embed @ Wi (+bi, row0=bi) via f16 MFMA, 2 m-tiles/wave ----------------
__global__ __launch_bounds__(256) void ewi_mfma(const float* __restrict__ embed,
                                                const half8* __restrict__ Wif,
                                                const float* __restrict__ biP,
                                                _Float16* __restrict__ EWi16) {
    const int tid  = threadIdx.x;
    const int w    = tid >> 6;
    const int lane = tid & 63;
    const int l15  = lane & 15;
    const int lhi  = lane >> 4;

    const int mtb   = (blockIdx.x * 4 + w) * 2;
    const bool liveA = (mtb < NTILE3);
    const bool liveB = (mtb + 1 < NTILE3);
    if (!liveA) return;                      // wave-uniform, kernel has no barriers
    const int i0a = mtb * 16;
    const int i0b = liveB ? (mtb + 1) * 16 : i0a;

    half8 aA[KTW], aB[KTW];
    #pragma unroll
    for (int kt = 0; kt < KTW; ++kt) {
        const int k0 = kt * 32 + lhi * 8;
        const float* erA = embed + (size_t)(i0a + l15) * EE + k0;
        const float* erB = embed + (size_t)(i0b + l15) * EE + k0;
        #pragma unroll
        for (int j = 0; j < 8; ++j) {
            aA[kt][j] = (k0 + j < EE) ? (_Float16)erA[j] : (_Float16)0.f;
            aB[kt][j] = (k0 + j < EE) ? (_Float16)erB[j] : (_Float16)0.f;
        }
    }

    for (int nt = 0; nt < NTW; ++nt) {
        const half8* bfp = Wif + (size_t)nt * KTW * 64 + lane;
        float4v accA = (float4v){0.f, 0.f, 0.f, 0.f};
        float4v accB = (float4v){0.f, 0.f, 0.f, 0.f};
        #pragma unroll
        for (int kt = 0; kt < KTW; ++kt) {
            const half8 bf = bfp[kt * 64];
            accA = mfma16(aA[kt], bf, accA);
            accB = mfma16(aB[kt], bf, accB);
        }
        const float biv = biP[nt * 16 + l15];
        #pragma unroll
        for (int r = 0; r < 4; ++r) {
            const int rowA = i0a + lhi * 4 + r;
            float valA = accA[r] + biv;
            if (rowA == 0) valA = biv;       // q==0 padding row: bias only
            EWi16[(size_t)rowA * 800 + nt * 16 + l15] = (_Float16)valA;
        }
        if (liveB) {
            #pragma unroll
            for (int r = 0; r < 4; ++r) {
                const int rowB = i0b + lhi * 4 + r;
                EWi16[(size_t)rowB * 800 + nt * 16 + l15] = (_Float16)(accB[r] + biv);
            }
        }
    }
}

// ---------------- K2: 8-wave weight-stationary MFMA GRU scan (R9 structure) ----------------
// 256 blocks x 512 threads (8 waves, 2/SIMD). Wave w owns tile-cols {w, w+8} x 3 gates.
// R14 changes vs R13 (both numerically identity -> absmax must stay 9.766e-4):
// (a) exec-masked af loads: only lanes l15<4 issue ds_read_b128 (rows 4-15 are zeros and
//     C rows 4-15 are never read) -> LDS read traffic 56->14 KB/CU/step, conflicts ~4x down.
// (b) waves 5-7 skip c2=1 (tc=13,14,15 are 100% padding): -21 MFMA + 3 accbuf writes each.
__global__ __launch_bounds__(512, 2) void scan_mfma(const int* __restrict__ q,
                                                    const _Float16* __restrict__ EWi16,
                                                    const half8* __restrict__ Whf,
                                                    _Float16* __restrict__ h16g) {
    __shared__ __align__(16) _Float16 hbuf[2][16 * HSTR];
    __shared__ __align__(16) float accbuf[16 * 49 * 4];   // [l15][tile][b]
    __shared__ int qs[4][TT];

    const int tid  = threadIdx.x;
    const int w    = tid >> 6;
    const int lane = tid & 63;
    const int l15  = lane & 15;
    const int lhi  = lane >> 4;     // = batch row b in combine
    const int b0   = blockIdx.x * 4;

    // init: h = 0 everywhere except col 200 = 1 (bhn-fold constant; never overwritten)
    for (int idx = tid; idx < 2 * 16 * HSTR; idx += 512)
        ((_Float16*)hbuf)[idx] = (idx % HSTR == HH) ? (_Float16)1.0f : (_Float16)0.f;
    for (int idx = tid; idx < 4 * TT; idx += 512) {
        int b = idx / TT, t = idx % TT;
        qs[b][t] = q[(size_t)(b0 + b) * TT + t];
    }

    // --- register-resident Wh fragments: [gate][c2][kt] ---
    half8 wb[3][2][7];
    #pragma unroll
    for (int g = 0; g < 3; ++g) {
        #pragma unroll
        for (int c2 = 0; c2 < 2; ++c2) {
            const int tc = w + c2 * 8;
            #pragma unroll
            for (int kt = 0; kt < NKT; ++kt)
                wb[g][c2][kt] = Whf[((size_t)(g * 16 + tc) * NKT + kt) * 64 + lane];
        }
    }

    const int col0 = w * 16 + l15;            // 0..127, always valid
    const int col1 = 128 + w * 16 + l15;      // 128..255, valid iff < 200
    const bool v1  = (col1 < HH);
    const bool v1w = (w < 5);                 // wave-uniform: tc=w+8 has any real col
    const int colw1 = v1 ? col1 : 236;        // dump slot (never read/exported)

    half8 zero8;
    #pragma unroll
    for (int j = 0; j < 8; ++j) zero8[j] = (_Float16)0.f;

    float hreg0 = 0.f, hreg1 = 0.f;           // h_old for (b=lhi, col0/col1)

    __syncthreads();

    half4v giA0, giA1, giB0, giB1;
    #define LOADGI(d0, d1, tt) do {                                          \
        const int tl = (tt) < TT ? (tt) : (TT - 1);                          \
        const int qv = qs[lhi][tl];                                          \
        const _Float16* ew = EWi16 + (size_t)qv * 800;                       \
        d0 = *(const half4v*)(ew + col0 * 4);                                \
        d1 = *(const half4v*)(ew + col1 * 4);                                \
    } while (0)

    LOADGI(giA0, giA1, 0);
    LOADGI(giB0, giB1, 1);

    #define STEP(CUR, NXT, G0, G1, TLOAD) do {                               \
        /* consume gi early, then immediately refill with t+2 prefetch */    \
        const float c0r = (float)G0[0], c0z = (float)G0[1], c0n = (float)G0[2]; \
        const float c1r = (float)G1[0], c1z = (float)G1[1], c1n = (float)G1[2]; \
        LOADGI(G0, G1, TLOAD);                                               \
        float4v acc[3][2];                                                   \
        _Pragma("unroll")                                                    \
        for (int g = 0; g < 3; ++g)                                          \
            _Pragma("unroll")                                                \
            for (int c2 = 0; c2 < 2; ++c2)                                   \
                acc[g][c2] = (float4v){0.f, 0.f, 0.f, 0.f};                  \
        const _Float16* hb = &hbuf[CUR][0];                                  \
        _Pragma("unroll")                                                    \
        for (int kt = 0; kt < NKT; ++kt) {                                   \
            half8 af = zero8;                                                \
            if (l15 < 4)   /* rows 4-15 are zero; C rows 4-15 never read */  \
                af = *(const half8*)(hb + l15 * HSTR + kt * 32 + lhi * 8);   \
            _Pragma("unroll")                                                \
            for (int g = 0; g < 3; ++g) {                                    \
                acc[g][0] = mfma16(af, wb[g][0][kt], acc[g][0]);             \
                if (v1w) acc[g][1] = mfma16(af, wb[g][1][kt], acc[g][1]);    \
            }                                                                \
        }                                                                    \
        /* redistribute: lanes 0-15 hold rows 0-3 (the real batch) */        \
        if (lane < 16) {                                                     \
            _Pragma("unroll")                                                \
            for (int g = 0; g < 3; ++g) {                                    \
                *(float4v*)&accbuf[((l15 * 49) + (g * 16 + w)) * 4] = acc[g][0]; \
                if (v1w)                                                     \
                    *(float4v*)&accbuf[((l15 * 49) + (g * 16 + w + 8)) * 4] = acc[g][1]; \
            }                                                                \
        }                                                                    \
        /* dense combine: lane -> (b=lhi, col0|col1); bhn already in aN */   \
        _Float16* hn = &hbuf[NXT][0];                                        \
        {                                                                    \
            const int rowb = l15 * 49 * 4 + lhi;                             \
            float aR0 = accbuf[rowb + (0 * 16 + w) * 4];                     \
            float aZ0 = accbuf[rowb + (1 * 16 + w) * 4];                     \
            float aN0 = accbuf[rowb + (2 * 16 + w) * 4];                     \
            float r0 = sigm(c0r + aR0);                                      \
            float z0 = sigm(c0z + aZ0);                                      \
            float n0 = tanh_fast(c0n + r0 * aN0);                            \
            float hv0 = (1.f - z0) * n0 + z0 * hreg0;                        \
            hreg0 = hv0;                                                     \
            hn[lhi * HSTR + col0] = (_Float16)hv0;                           \
            if (v1w) {                                                       \
                float aR1 = accbuf[rowb + (0 * 16 + w + 8) * 4];             \
                float aZ1 = accbuf[rowb + (1 * 16 + w + 8) * 4];             \
                float aN1 = accbuf[rowb + (2 * 16 + w + 8) * 4];             \
                float r1 = sigm(c1r + aR1);                                  \
                float z1 = sigm(c1z + aZ1);                                  \
                float n1 = tanh_fast(c1n + r1 * aN1);                        \
                float hv1 = (1.f - z1) * n1 + z1 * hreg1;                    \
                hreg1 = hv1;                                                 \
                hn[lhi * HSTR + colw1] = (_Float16)hv1;                      \
            }                                                                \
        }                                                                    \
        __syncthreads();                                                     \
    } while (0)

    for (int t = 0; t < TT; t += 2) {
        STEP(0, 1, giA0, giA1, t + 2);
        STEP(1, 0, giB0, giB1, t + 3);
    }
    #undef STEP
    #undef LOADGI

    // ---- export h_last (rows 0-3; col 200 = 1 harmless: Wo frags zero for k>=200) ----
    for (int idx = tid; idx < 4 * KPAD; idx += 512) {
        int b = idx / KPAD, k = idx % KPAD;
        h16g[(size_t)(b0 + b) * KPAD + k] = hbuf[0][b * HSTR + k];
    }
}

// ---------------- K3: out = h_last @ Wo + bo via f16 MFMA, 2 n-tiles/wave ----------------
__global__ __launch_bounds__(256) void out_mfma(const _Float16* __restrict__ h16g,
                                                const float* __restrict__ Wo,
                                                const float* __restrict__ bo,
                                                float* __restrict__ out) {
    const int tid  = threadIdx.x;
    const int w    = tid >> 6;
    const int lane = tid & 63;
    const int l15  = lane & 15;
    const int lhi  = lane >> 4;

    const int ntb   = (blockIdx.x * 4 + w) * 2;
    const bool liveA = (ntb < NTILE3);
    const bool liveB = (ntb + 1 < NTILE3);
    const int ntA = liveA ? ntb : (NTILE3 - 1);
    const int ntB = liveB ? (ntb + 1) : (NTILE3 - 1);
    const int colA = ntA * 16 + l15;
    const int colB = ntB * 16 + l15;

    half8 wbA[7], wbB[7];
    #pragma unroll
    for (int kt = 0; kt < NKT; ++kt) {
        #pragma unroll
        for (int j = 0; j < 8; ++j) {
            int k = kt * 32 + lhi * 8 + j;
            wbA[kt][j] = (k < HH) ? (_Float16)Wo[(size_t)k * NI + colA] : (_Float16)0.f;
            wbB[kt][j] = (k < HH) ? (_Float16)Wo[(size_t)k * NI + colB] : (_Float16)0.f;
        }
    }
    const float bovA = bo[colA];
    const float bovB = bo[colB];

    for (int mt = 0; mt < BATCH / 16; ++mt) {
        const _Float16* hrow = h16g + (size_t)(mt * 16 + l15) * KPAD + lhi * 8;
        float4v accA = (float4v){0.f, 0.f, 0.f, 0.f};
        float4v accB = (float4v){0.f, 0.f, 0.f, 0.f};
        #pragma unroll
        for (int kt = 0; kt < NKT; ++kt) {
            const half8 af = *(const half8*)(hrow + kt * 32);
            accA = mfma16(af, wbA[kt], accA);
            accB = mfma16(af, wbB[kt], accB);
        }
        if (liveA) {
            #pragma unroll
            for (int r = 0; r < 4; ++r) {
                int row = mt * 16 + lhi * 4 + r;
                out[(size_t)row * NI + colA] = accA[r] + bovA;
            }
        }
        if (liveB) {
            #pragma unroll
            for (int r = 0; r < 4; ++r) {
                int row = mt * 16 + lhi * 4 + r;
                out[(size_t)row * NI + colB] = accB[r] + bovB;
            }
        }
    }
}

extern "C" void kernel_launch(void* const* d_in, const int* in_sizes, int n_in,
                              void* d_out, int out_size, void* d_ws, size_t ws_size,
                              hipStream_t stream) {
    const int*   q     = (const int*)d_in[0];
    const float* embed = (const float*)d_in[1];
    const float* Wi    = (const float*)d_in[2];
    const float* bi    = (const float*)d_in[3];
    const float* Wh    = (const float*)d_in[4];
    const float* bhn   = (const float*)d_in[5];
    const float* Wo    = (const float*)d_in[6];
    const float* bo    = (const float*)d_in[7];
    float* out = (float*)d_out;

    // Scratch layout in d_out (204.8 MB), consumed before K3 overwrites it:
    //   EWi16 [50000 x 200 x 4] f16 = 80,000,000 B at +0
    //   Whf   [48*7 frags]      f16 =    344,064 B at +120,000,000
    //   Wif   [50*4 frags]      f16 =    204,800 B at +121,000,000
    //   biP   [800]             f32 =      3,200 B at +122,000,000
    //   h16g  [1024 x 224] f16 = 458,752 B in d_ws
    _Float16* EWi16 = (_Float16*)d_out;
    half8*    Whf   = (half8*)((char*)d_out + 120000000);
    half8*    Wif   = (half8*)((char*)d_out + 121000000);
    float*    biP   = (float*)((char*)d_out + 122000000);
    _Float16* h16g  = (_Float16*)d_ws;

    repack_all<<<NTW * KTW + 48 * NKT, 64, 0, stream>>>(Wi, bi, Wh, bhn, Wif, biP, Whf);
    ewi_mfma<<<(NTILE3 / 2 + 3) / 4, 256, 0, stream>>>(embed, Wif, biP, EWi16);
    scan_mfma<<<BATCH / 4, 512, 0, stream>>>(q, EWi16, Whf, h16g);
    out_mfma<<<(NTILE3 / 2 + 3) / 4 + 1, 256, 0, stream>>>(h16g, Wo, bo, out);
}

// Round 15
// 371.908 us; speedup vs baseline: 1.0859x; 1.0859x over previous
//
#include <hip/hip_runtime.h>

#define BATCH 1024
#define TT    200
#define EE    100
#define HH    200
#define GG    600   // 3*HH
#define NI    50000
#define NKT   7     // scan k-tiles: 224 = 7*32 (K=200 padded; col 200 = constant 1 for bhn fold)
#define KPAD  224
#define HSTR  264   // LDS h row stride in f16
#define NTILE3 3125 // 50000/16 output n-tiles
#define NTW   50    // ewi n'-tiles: N'=800 = 50*16
#define KTW   4     // ewi k-tiles: K=100 padded to 128

typedef _Float16 half8 __attribute__((ext_vector_type(8)));
typedef _Float16 half4v __attribute__((ext_vector_type(4)));
typedef float   float4v __attribute__((ext_vector_type(4)));

static __device__ __forceinline__ float4v mfma16(half8 a, half8 b, float4v c) {
    return __builtin_amdgcn_mfma_f32_16x16x32_f16(a, b, c, 0, 0, 0);
}

#if __has_builtin(__builtin_amdgcn_rcpf)
static __device__ __forceinline__ float fastrcp(float x) { return __builtin_amdgcn_rcpf(x); }
#else
static __device__ __forceinline__ float fastrcp(float x) { return 1.f / x; }
#endif

static __device__ __forceinline__ float sigm(float x) {
    return fastrcp(1.f + __expf(-x));
}
static __device__ __forceinline__ float tanh_fast(float x) {
    float e = __expf(2.f * fabsf(x));
    float t = 1.f - 2.f * fastrcp(e + 1.f);
    return __builtin_copysignf(t, x);
}

// ---------------- K0: fused repack of Wi (+biP) and Wh (+bhn fold) into f16 MFMA B-frags ----
// bx < 200: Wif[(nt*4+kt)*64+lane], n'=4c+g packing; bx >= 200: Whf (48 gate-tiles x 7 kt).
// bhn fold: n-gate (g==2) row k==200 carries bhn[col]; scan keeps h[200] == 1 so the MFMA
// accumulates bhn into aN directly.
__global__ __launch_bounds__(64) void repack_all(const float* __restrict__ Wi,
                                                 const float* __restrict__ bi,
                                                 const float* __restrict__ Wh,
                                                 const float* __restrict__ bhn,
                                                 half8* __restrict__ Wif,
                                                 float* __restrict__ biP,
                                                 half8* __restrict__ Whf) {
    const int bx   = blockIdx.x;
    const int lane = threadIdx.x;
    const int l15  = lane & 15;
    const int lhi  = lane >> 4;
    if (bx < NTW * KTW) {
        const int kt = bx & 3;
        const int nt = bx >> 2;
        const int np = nt * 16 + l15;     // n' in [0,800)
        const int c  = np >> 2;
        const int g  = np & 3;
        half8 v;
        #pragma unroll
        for (int j = 0; j < 8; ++j) {
            int k = kt * 32 + lhi * 8 + j;
            float w = (k < EE && g < 3) ? Wi[(size_t)k * GG + g * HH + c] : 0.f;
            v[j] = (_Float16)w;
        }
        Wif[(size_t)bx * 64 + lane] = v;
        if (kt == 0 && lhi == 0)
            biP[np] = (g < 3) ? bi[g * HH + c] : 0.f;
    } else {
        const int b2   = bx - NTW * KTW;   // 0..335
        const int kt   = b2 % NKT;
        const int tile = b2 / NKT;
        const int g    = tile / 16;
        const int tc   = tile % 16;
        const int col  = tc * 16 + l15;
        half8 v;
        #pragma unroll
        for (int j = 0; j < 8; ++j) {
            int k = kt * 32 + lhi * 8 + j;
            float w = 0.f;
            if (col < HH) {
                if (k < HH)                      w = Wh[(size_t)k * GG + g * HH + col];
                else if (g == 2 && k == HH)      w = bhn[col];   // bhn fold row
            }
            v[j] = (_Float16)w;
        }
        Whf[(size_t)b2 * 64 + lane] = v;
    }
}

// ---------------- K1: EWi16 = embed @ Wi (+bi, row0=bi) via f16 MFMA, 2 m-tiles/wave ----------------
__global__ __launch_bounds__(256) void ewi_mfma(const float* __restrict__ embed,
                                                const half8* __restrict__ Wif,
                                                const float* __restrict__ biP,
                                                _Float16* __restrict__ EWi16) {
    const int tid  = threadIdx.x;
    const int w    = tid >> 6;
    const int lane = tid & 63;
    const int l15  = lane & 15;
    const int lhi  = lane >> 4;

    const int mtb   = (blockIdx.x * 4 + w) * 2;
    const bool liveA = (mtb < NTILE3);
    const bool liveB = (mtb + 1 < NTILE3);
    if (!liveA) return;                      // wave-uniform, kernel has no barriers
    const int i0a = mtb * 16;
    const int i0b = liveB ? (mtb + 1) * 16 : i0a;

    half8 aA[KTW], aB[KTW];
    #pragma unroll
    for (int kt = 0; kt < KTW; ++kt) {
        const int k0 = kt * 32 + lhi * 8;
        const float* erA = embed + (size_t)(i0a + l15) * EE + k0;
        const float* erB = embed + (size_t)(i0b + l15) * EE + k0;
        #pragma unroll
        for (int j = 0; j < 8; ++j) {
            aA[kt][j] = (k0 + j < EE) ? (_Float16)erA[j] : (_Float16)0.f;
            aB[kt][j] = (k0 + j < EE) ? (_Float16)erB[j] : (_Float16)0.f;
        }
    }

    for (int nt = 0; nt < NTW; ++nt) {
        const half8* bfp = Wif + (size_t)nt * KTW * 64 + lane;
        float4v accA = (float4v){0.f, 0.f, 0.f, 0.f};
        float4v accB = (float4v){0.f, 0.f, 0.f, 0.f};
        #pragma unroll
        for (int kt = 0; kt < KTW; ++kt) {
            const half8 bf = bfp[kt * 64];
            accA = mfma16(aA[kt], bf, accA);
            accB = mfma16(aB[kt], bf, accB);
        }
        const float biv = biP[nt * 16 + l15];
        #pragma unroll
        for (int r = 0; r < 4; ++r) {
            const int rowA = i0a + lhi * 4 + r;
            float valA = accA[r] + biv;
            if (rowA == 0) valA = biv;       // q==0 padding row: bias only
            EWi16[(size_t)rowA * 800 + nt * 16 + l15] = (_Float16)valA;
        }
        if (liveB) {
            #pragma unroll
            for (int r = 0; r < 4; ++r) {
                const int rowB = i0b + lhi * 4 + r;
                EWi16[(size_t)rowB * 800 + nt * 16 + l15] = (_Float16)(accB[r] + biv);
            }
        }
    }
}

// ---------------- K2: 8-wave weight-stationary MFMA GRU scan (R9 structure, measured best) ----
// 256 blocks x 512 threads (8 waves, 2/SIMD). Wave w owns tile-cols {w, w+8} x 3 gates
// (42 stationary B-frags). Same-wave accbuf staging -> ONE barrier per step.
// Measured-converged optimum: R10 (transposed) 327us, R11 (4-wave) 352us, R12 (12-wave
// balanced) 293us, R14 (exec-masked loads, -3.4x bank conflicts) 295us -- all worse than
// this structure's 264us. Step = 3170 cy vs 1630 cy MFMA-pipe floor; the residual is the
// phase-locked recurrence chain (all waves traverse ds_read->MFMA->stage->combine->barrier
// in lockstep; h(t)->h(t+1) dependency forbids stagger). Bank conflicts (1.76e7) are
// hidden under the MFMA phase (removing them changed nothing: R7->R9, R14).
__global__ __launch_bounds__(512, 2) void scan_mfma(const int* __restrict__ q,
                                                    const _Float16* __restrict__ EWi16,
                                                    const half8* __restrict__ Whf,
                                                    _Float16* __restrict__ h16g) {
    __shared__ __align__(16) _Float16 hbuf[2][16 * HSTR];
    __shared__ __align__(16) float accbuf[16 * 49 * 4];   // [l15][tile][b]
    __shared__ int qs[4][TT];

    const int tid  = threadIdx.x;
    const int w    = tid >> 6;
    const int lane = tid & 63;
    const int l15  = lane & 15;
    const int lhi  = lane >> 4;     // = batch row b in combine
    const int b0   = blockIdx.x * 4;

    // init: h = 0 everywhere except col 200 = 1 (bhn-fold constant; never overwritten:
    // combine writes cols <200 or dump slot 236)
    for (int idx = tid; idx < 2 * 16 * HSTR; idx += 512)
        ((_Float16*)hbuf)[idx] = (idx % HSTR == HH) ? (_Float16)1.0f : (_Float16)0.f;
    for (int idx = tid; idx < 4 * TT; idx += 512) {
        int b = idx / TT, t = idx % TT;
        qs[b][t] = q[(size_t)(b0 + b) * TT + t];
    }

    // --- register-resident Wh fragments: [gate][c2][kt] ---
    half8 wb[3][2][7];
    #pragma unroll
    for (int g = 0; g < 3; ++g) {
        #pragma unroll
        for (int c2 = 0; c2 < 2; ++c2) {
            const int tc = w + c2 * 8;
            #pragma unroll
            for (int kt = 0; kt < NKT; ++kt)
                wb[g][c2][kt] = Whf[((size_t)(g * 16 + tc) * NKT + kt) * 64 + lane];
        }
    }

    const int col0 = w * 16 + l15;            // 0..127, always valid
    const int col1 = 128 + w * 16 + l15;      // 128..255, valid iff < 200
    const bool v1  = (col1 < HH);
    const int colw1 = v1 ? col1 : 236;        // dump slot (never read/exported)

    float hreg0 = 0.f, hreg1 = 0.f;           // h_old for (b=lhi, col0/col1)

    __syncthreads();

    half4v giA0, giA1, giB0, giB1;
    #define LOADGI(d0, d1, tt) do {                                          \
        const int tl = (tt) < TT ? (tt) : (TT - 1);                          \
        const int qv = qs[lhi][tl];                                          \
        const _Float16* ew = EWi16 + (size_t)qv * 800;                       \
        d0 = *(const half4v*)(ew + col0 * 4);                                \
        d1 = *(const half4v*)(ew + col1 * 4);                                \
    } while (0)

    LOADGI(giA0, giA1, 0);
    LOADGI(giB0, giB1, 1);

    #define STEP(CUR, NXT, G0, G1, TLOAD) do {                               \
        /* consume gi early, then immediately refill with t+2 prefetch */    \
        const float c0r = (float)G0[0], c0z = (float)G0[1], c0n = (float)G0[2]; \
        const float c1r = (float)G1[0], c1z = (float)G1[1], c1n = (float)G1[2]; \
        LOADGI(G0, G1, TLOAD);                                               \
        float4v acc[3][2];                                                   \
        _Pragma("unroll")                                                    \
        for (int g = 0; g < 3; ++g)                                          \
            _Pragma("unroll")                                                \
            for (int c2 = 0; c2 < 2; ++c2)                                   \
                acc[g][c2] = (float4v){0.f, 0.f, 0.f, 0.f};                  \
        const _Float16* hb = &hbuf[CUR][0];                                  \
        _Pragma("unroll")                                                    \
        for (int kt = 0; kt < NKT; ++kt) {                                   \
            const half8 af = *(const half8*)(hb + l15 * HSTR + kt * 32 + lhi * 8); \
            _Pragma("unroll")                                                \
            for (int g = 0; g < 3; ++g) {                                    \
                acc[g][0] = mfma16(af, wb[g][0][kt], acc[g][0]);             \
                acc[g][1] = mfma16(af, wb[g][1][kt], acc[g][1]);             \
            }                                                                \
        }                                                                    \
        /* redistribute: lanes 0-15 hold rows 0-3 (the real batch) */        \
        if (lane < 16) {                                                     \
            _Pragma("unroll")                                                \
            for (int g = 0; g < 3; ++g)                                      \
                _Pragma("unroll")                                            \
                for (int c2 = 0; c2 < 2; ++c2)                               \
                    *(float4v*)&accbuf[((l15 * 49) + (g * 16 + w + c2 * 8)) * 4] = acc[g][c2]; \
        }                                                                    \
        /* dense combine: lane -> (b=lhi, col0|col1); bhn already in aN */   \
        _Float16* hn = &hbuf[NXT][0];                                        \
        {                                                                    \
            const int rowb = l15 * 49 * 4 + lhi;                             \
            float aR0 = accbuf[rowb + (0 * 16 + w) * 4];                     \
            float aZ0 = accbuf[rowb + (1 * 16 + w) * 4];                     \
            float aN0 = accbuf[rowb + (2 * 16 + w) * 4];                     \
            float aR1 = accbuf[rowb + (0 * 16 + w + 8) * 4];                 \
            float aZ1 = accbuf[rowb + (1 * 16 + w + 8) * 4];                 \
            float aN1 = accbuf[rowb + (2 * 16 + w + 8) * 4];                 \
            float r0 = sigm(c0r + aR0);                                      \
            float z0 = sigm(c0z + aZ0);                                      \
            float n0 = tanh_fast(c0n + r0 * aN0);                            \
            float hv0 = (1.f - z0) * n0 + z0 * hreg0;                        \
            hreg0 = hv0;                                                     \
            hn[lhi * HSTR + col0] = (_Float16)hv0;                           \
            float r1 = sigm(c1r + aR1);                                      \
            float z1 = sigm(c1z + aZ1);                                      \
            float n1 = tanh_fast(c1n + r1 * aN1);                            \
            float hv1 = (1.f - z1) * n1 + z1 * hreg1;                        \
            hreg1 = hv1;                                                     \
            hn[lhi * HSTR + colw1] = (_Float16)hv1;                          \
        }                                                                    \
        __syncthreads();                                                     \
    } while (0)

    for (int t = 0; t < TT; t += 2) {
        STEP(0, 1, giA0, giA1, t + 2);
        STEP(1, 0, giB0, giB1, t + 3);
    }
    #undef STEP
    #undef LOADGI

    // ---- export h_last (rows 0-3; col 200 = 1 harmless: Wo frags zero for k>=200) ----
    for (int idx = tid; idx < 4 * KPAD; idx += 512) {
        int b = idx / KPAD, k = idx % KPAD;
        h16g[(size_t)(b0 + b) * KPAD + k] = hbuf[0][b * HSTR + k];
    }
}

// ---------------- K3: out = h_last @ Wo + bo via f16 MFMA, 2 n-tiles/wave ----------------
__global__ __launch_bounds__(256) void out_mfma(const _Float16* __restrict__ h16g,
                                                const float* __restrict__ Wo,
                                                const float* __restrict__ bo,
                                                float* __restrict__ out) {
    const int tid  = threadIdx.x;
    const int w    = tid >> 6;
    const int lane = tid & 63;
    const int l15  = lane & 15;
    const int lhi  = lane >> 4;

    const int ntb   = (blockIdx.x * 4 + w) * 2;
    const bool liveA = (ntb < NTILE3);
    const bool liveB = (ntb + 1 < NTILE3);
    const int ntA = liveA ? ntb : (NTILE3 - 1);
    const int ntB = liveB ? (ntb + 1) : (NTILE3 - 1);
    const int colA = ntA * 16 + l15;
    const int colB = ntB * 16 + l15;

    half8 wbA[7], wbB[7];
    #pragma unroll
    for (int kt = 0; kt < NKT; ++kt) {
        #pragma unroll
        for (int j = 0; j < 8; ++j) {
            int k = kt * 32 + lhi * 8 + j;
            wbA[kt][j] = (k < HH) ? (_Float16)Wo[(size_t)k * NI + colA] : (_Float16)0.f;
            wbB[kt][j] = (k < HH) ? (_Float16)Wo[(size_t)k * NI + colB] : (_Float16)0.f;
        }
    }
    const float bovA = bo[colA];
    const float bovB = bo[colB];

    for (int mt = 0; mt < BATCH / 16; ++mt) {
        const _Float16* hrow = h16g + (size_t)(mt * 16 + l15) * KPAD + lhi * 8;
        float4v accA = (float4v){0.f, 0.f, 0.f, 0.f};
        float4v accB = (float4v){0.f, 0.f, 0.f, 0.f};
        #pragma unroll
        for (int kt = 0; kt < NKT; ++kt) {
            const half8 af = *(const half8*)(hrow + kt * 32);
            accA = mfma16(af, wbA[kt], accA);
            accB = mfma16(af, wbB[kt], accB);
        }
        if (liveA) {
            #pragma unroll
            for (int r = 0; r < 4; ++r) {
                int row = mt * 16 + lhi * 4 + r;
                out[(size_t)row * NI + colA] = accA[r] + bovA;
            }
        }
        if (liveB) {
            #pragma unroll
            for (int r = 0; r < 4; ++r) {
                int row = mt * 16 + lhi * 4 + r;
                out[(size_t)row * NI + colB] = accB[r] + bovB;
            }
        }
    }
}

extern "C" void kernel_launch(void* const* d_in, const int* in_sizes, int n_in,
                              void* d_out, int out_size, void* d_ws, size_t ws_size,
                              hipStream_t stream) {
    const int*   q     = (const int*)d_in[0];
    const float* embed = (const float*)d_in[1];
    const float* Wi    = (const float*)d_in[2];
    const float* bi    = (const float*)d_in[3];
    const float* Wh    = (const float*)d_in[4];
    const float* bhn   = (const float*)d_in[5];
    const float* Wo    = (const float*)d_in[6];
    const float* bo    = (const float*)d_in[7];
    float* out = (float*)d_out;

    // Scratch layout in d_out (204.8 MB), consumed before K3 overwrites it:
    //   EWi16 [50000 x 200 x 4] f16 = 80,000,000 B at +0
    //   Whf   [48*7 frags]      f16 =    344,064 B at +120,000,000
    //   Wif   [50*4 frags]      f16 =    204,800 B at +121,000,000
    //   biP   [800]             f32 =      3,200 B at +122,000,000
    //   h16g  [1024 x 224] f16 = 458,752 B in d_ws
    _Float16* EWi16 = (_Float16*)d_out;
    half8*    Whf   = (half8*)((char*)d_out + 120000000);
    half8*    Wif   = (half8*)((char*)d_out + 121000000);
    float*    biP   = (float*)((char*)d_out + 122000000);
    _Float16* h16g  = (_Float16*)d_ws;

    repack_all<<<NTW * KTW + 48 * NKT, 64, 0, stream>>>(Wi, bi, Wh, bhn, Wif, biP, Whf);
    ewi_mfma<<<(NTILE3 / 2 + 3) / 4, 256, 0, stream>>>(embed, Wif, biP, EWi16);
    scan_mfma<<<BATCH / 4, 512, 0, stream>>>(q, EWi16, Whf, h16g);
    out_mfma<<<(NTILE3 / 2 + 3) / 4 + 1, 256, 0, stream>>>(h16g, Wo, bo, out);
}